// Round 5
// baseline (494.418 us; speedup 1.0000x reference)
//
#include <hip/hip_runtime.h>
#include <hip/hip_bf16.h>
#include <stdint.h>

#define BB 4
#define NN 16384
#define CC 128
#define MM 2048
#define KNN 16
#define QCAPG 512
#define EPS 1e-3f

typedef unsigned int u32;
typedef unsigned long long u64;

// ---- workspace layout (bytes) ----
#define OFF_FEATT   0ull                    // B*N*C f32   = 33554432
#define OFF_PTS4    33554432ull             // B*N float4  =  4194304
#define OFF_WT      37748736ull             // C*C f32     =    65536
#define OFF_KEYS    37814272ull             // B*N u64     =   524288
#define OFF_VEC     38338560ull             // B*C u32     =     2048
#define OFF_IDX     38340608ull             // B*M u32     =    32768
#define OFF_VAL     38373376ull             // B*M f32     =    32768
#define OFF_TMP1    38406144ull             // B*4*2048 u64=   262144
#define OFF_TMP2    38668288ull             // B*2*2048 u64=   131072
#define OFF_T       38799360ull             // 8192 f32    =    32768
#define OFF_QCNT    38832128ull             // 8192 u32    =    32768
#define OFF_Q       38864896ull             // 8192*512 u32= 16777216  (end ~55.6MB)

// numpy-exact f32 distance: ((pw + nw) - 2*(x*nx + y*ny + z*nz)), no FMA
__device__ __forceinline__ float np_dist(float4 p, float4 nd) {
#pragma clang fp contract(off)
    float dot = ((p.x * nd.x) + (p.y * nd.y)) + (p.z * nd.z);
    float d = (p.w + nd.w) - 2.0f * dot;
    return d;
}

// fast screening value s = -2*dot + p.w  (node-|n|^2 excluded; any rounding ok)
__device__ __forceinline__ float sfast(float4 p, float4 nd) {
    float dot = fmaf(p.x, nd.x, fmaf(p.y, nd.y, p.z * nd.z));
    return fmaf(-2.0f, dot, p.w);
}

__device__ __forceinline__ u32 mono_bits(float d) {
    u32 u = __float_as_uint(d);
    u ^= ((u32)(((int)u) >> 31)) | 0x80000000u;
    return u;
}

// 16th smallest of the 64 per-lane values (each lane-min covers disjoint points)
__device__ __forceinline__ float kth16(float v, int l) {
    float sv = v;
#pragma unroll
    for (int k = 2; k <= 64; k <<= 1) {
#pragma unroll
        for (int j = k >> 1; j > 0; j >>= 1) {
            float pv = __shfl_xor(sv, j);
            bool up = ((l & k) == 0);
            bool tmin = (((l & j) == 0) == up);
            float mn = fminf(sv, pv), mx = fmaxf(sv, pv);
            sv = tmin ? mn : mx;
        }
    }
    return __shfl(sv, 15);
}

// fused prep: pts4 (numpy-exact |p|^2), WT transpose, vecU zero, qcnt zero
__global__ void k_prep(const float* __restrict__ coords, const float* __restrict__ W,
                       float4* __restrict__ pts4, float* __restrict__ WT,
                       u32* __restrict__ vecU, u32* __restrict__ qcnt) {
    int g = blockIdx.x * 256 + threadIdx.x;
    if (g < BB * NN) {
        int b = g >> 14, n = g & (NN - 1);
        const float* cb = coords + (size_t)b * 3 * NN;
        float x = cb[n], y = cb[NN + n], z = cb[2 * NN + n];
        float w;
        {
#pragma clang fp contract(off)
            w = ((x * x) + (y * y)) + (z * z);
        }
        pts4[g] = make_float4(x, y, z, w);
    } else if (g < BB * NN + CC * CC) {
        int i = g - BB * NN;
        int o = i >> 7, c = i & 127;
        WT[c * CC + o] = W[i];
    } else if (g < BB * NN + CC * CC + BB * CC) {
        vecU[g - BB * NN - CC * CC] = 0u;
    } else if (g < BB * NN + CC * CC + BB * CC + BB * MM) {
        qcnt[g - BB * NN - CC * CC - BB * CC] = 0u;
    }
}

// fused transpose + vector-GEMV-max:
//   feat_t[b][n][c] = feats[b][c][n]; vector[b][o] = max_n relu(W@Z + b)
__global__ __launch_bounds__(256) void k_tv(const float* __restrict__ feats,
        const float* __restrict__ WT, const float* __restrict__ bias,
        float* __restrict__ feat_t, u32* __restrict__ vecU) {
    __shared__ float t[CC][65];
    int bx = blockIdx.x;                 // B * (N/64)
    int b = bx >> 8; int n0 = (bx & 255) * 64;
    int tid = threadIdx.x, l = tid & 63;
    int w = __builtin_amdgcn_readfirstlane(tid >> 6);
    const float* fb = feats + (size_t)b * CC * NN + n0;
    // load 128c x 64n tile (coalesced rows)
#pragma unroll
    for (int p = 0; p < 32; ++p) {
        int r = p * 4 + w;
        t[r][l] = fb[(size_t)r * NN + l];
    }
    __syncthreads();
    // write transposed (coalesced in c)
    float* ob = feat_t + ((size_t)b * NN + n0) * CC;
#pragma unroll
    for (int p = 0; p < 32; ++p) {
        int r = (p >> 1) * 4 + w;
        int c = (p & 1) * 64 + l;
        ob[(size_t)r * CC + c] = t[c][r];
    }
    // GEMV: wave w computes outputs [w*32, w*32+32) for all 64 n's
    int o0 = w * 32;
    float acc[32];
#pragma unroll
    for (int oi = 0; oi < 32; ++oi) acc[oi] = bias[o0 + oi];
    for (int c = 0; c < CC; ++c) {
        float zc = t[c][l];
        const float4* wt4 = (const float4*)(WT + c * CC + o0);
#pragma unroll
        for (int q = 0; q < 8; ++q) {
            float4 wv = wt4[q];
            acc[q * 4 + 0] = fmaf(wv.x, zc, acc[q * 4 + 0]);
            acc[q * 4 + 1] = fmaf(wv.y, zc, acc[q * 4 + 1]);
            acc[q * 4 + 2] = fmaf(wv.z, zc, acc[q * 4 + 2]);
            acc[q * 4 + 3] = fmaf(wv.w, zc, acc[q * 4 + 3]);
        }
    }
#pragma unroll
    for (int oi = 0; oi < 32; ++oi) {
        float rv = acc[oi] > 0.0f ? acc[oi] : 0.0f;   // relu, +0.0 guaranteed
#pragma unroll
        for (int s = 32; s; s >>= 1) rv = fmaxf(rv, __shfl_xor(rv, s));
        if (l == 0) atomicMax(vecU + b * CC + o0 + oi, __float_as_uint(rv));
    }
}

// keys[b][n] = (mono(sigmoid(sum_c feats*vector)) << 32) | (~n)
__global__ void k_scores(const float* __restrict__ feats, const float* __restrict__ vecF,
                         u64* __restrict__ keys) {
    int i = blockIdx.x * 256 + threadIdx.x;    // < B*N
    int b = i >> 14, n = i & (NN - 1);
    const float* fb = feats + (size_t)b * CC * NN + n;
    const float* vb = vecF + b * CC;
    float wsum = 0.f;
#pragma unroll 8
    for (int c = 0; c < CC; ++c) wsum = fmaf(fb[(size_t)c * NN], vb[c], wsum);
    float s = 1.0f / (1.0f + expf(-wsum));     // scores >= 0 -> bits monotonic
    u32 mono = __float_as_uint(s);
    keys[i] = ((u64)mono << 32) | (u64)(0xFFFFFFFFu - (u32)n);
}

// sort one 2048-key chunk descending, in place (32 blocks)
__global__ __launch_bounds__(512) void k_sortchunk(u64* __restrict__ keys) {
    __shared__ u64 sk[2048];
    int b = blockIdx.x >> 3, c = blockIdx.x & 7;
    int tid = threadIdx.x;
    u64* src = keys + (size_t)b * NN + c * 2048;
#pragma unroll
    for (int j = 0; j < 4; ++j) sk[tid + 512 * j] = src[tid + 512 * j];
    for (int size = 2; size <= 2048; size <<= 1) {
        for (int stride = size >> 1; stride > 0; stride >>= 1) {
            __syncthreads();
            for (int t = tid; t < 1024; t += 512) {
                int i = (t << 1) - (t & (stride - 1));
                int j = i + stride;
                u64 a = sk[i], cc = sk[j];
                bool up = ((i & size) == 0);
                if ((a < cc) == up) { sk[i] = cc; sk[j] = a; }
            }
        }
    }
    __syncthreads();
#pragma unroll
    for (int j = 0; j < 4; ++j) src[tid + 512 * j] = sk[tid + 512 * j];
}

// merge two descending 2048-lists -> top-2048 (descending)
__global__ __launch_bounds__(512) void k_mergetop(const u64* __restrict__ in,
        u64* __restrict__ outp, int lg /* log2(pairs per batch) */) {
    __shared__ u64 mk[4096];
    int b = blockIdx.x >> lg, pr = blockIdx.x & ((1 << lg) - 1);
    int tid = threadIdx.x;
    const u64* s0 = in + ((size_t)((b << lg) + pr) * 2) * 2048;
    const u64* s1 = s0 + 2048;
    for (int t = tid; t < 2048; t += 512) { mk[t] = s0[t]; mk[2048 + t] = s1[2047 - t]; }
    __syncthreads();
    for (int t = tid; t < 2048; t += 512) {
        u64 a = mk[t], c = mk[t + 2048];
        if (a < c) { mk[t] = c; mk[t + 2048] = a; }
    }
    for (int stride = 1024; stride > 0; stride >>= 1) {
        __syncthreads();
        for (int t = tid; t < 1024; t += 512) {
            int i = (t << 1) - (t & (stride - 1));
            int j = i + stride;
            u64 a = mk[i], c = mk[j];
            if (a < c) { mk[i] = c; mk[j] = a; }
        }
    }
    __syncthreads();
    u64* dst = outp + (size_t)((b << lg) + pr) * 2048;
    for (int t = tid; t < 2048; t += 512) dst[t] = mk[t];
}

// final merge -> idxA/valA
__global__ __launch_bounds__(512) void k_mergefinal(const u64* __restrict__ in,
        u32* __restrict__ idxA, float* __restrict__ valA) {
    __shared__ u64 mk[4096];
    int b = blockIdx.x, tid = threadIdx.x;
    const u64* s0 = in + (size_t)(b * 2) * 2048;
    const u64* s1 = s0 + 2048;
    for (int t = tid; t < 2048; t += 512) { mk[t] = s0[t]; mk[2048 + t] = s1[2047 - t]; }
    __syncthreads();
    for (int t = tid; t < 2048; t += 512) {
        u64 a = mk[t], c = mk[t + 2048];
        if (a < c) { mk[t] = c; mk[t + 2048] = a; }
    }
    for (int stride = 1024; stride > 0; stride >>= 1) {
        __syncthreads();
        for (int t = tid; t < 1024; t += 512) {
            int i = (t << 1) - (t & (stride - 1));
            int j = i + stride;
            u64 a = mk[i], c = mk[j];
            if (a < c) { mk[i] = c; mk[j] = a; }
        }
    }
    __syncthreads();
    for (int t = tid; t < 2048; t += 512) {
        u64 k = mk[t];
        idxA[b * MM + t] = 0xFFFFFFFFu - (u32)(k & 0xFFFFFFFFull);
        valA[b * MM + t] = __uint_as_float((u32)(k >> 32));
    }
}

// outputs 0,1 and first half of output 2
__global__ void k_gather(const float4* __restrict__ pts4, const float* __restrict__ feat_t,
        const u32* __restrict__ idxA, const float* __restrict__ valA, float* __restrict__ out) {
    int g = blockIdx.x * 256 + threadIdx.x;    // < B*M
    int b = g >> 11, i = g & (MM - 1);
    u32 n = idxA[g];
    float v = valA[g];
    float4 p = pts4[(b << 14) + (int)n];
    float* o0 = out + (size_t)b * 3 * MM + i;
    o0[0] = p.x; o0[MM] = p.y; o0[2 * MM] = p.z;
    float* o1 = o0 + 24576;
    o1[0] = p.x * v; o1[MM] = p.y * v; o1[2 * MM] = p.z * v;
    const float4* ft = (const float4*)(feat_t + ((size_t)(b << 14) + n) * CC);
    float* o2 = out + 49152 + ((size_t)b * 256) * MM + i;
#pragma unroll 8
    for (int q = 0; q < 32; ++q) {
        float4 f = ft[q];
        o2[(size_t)(4 * q + 0) * MM] = f.x * v;
        o2[(size_t)(4 * q + 1) * MM] = f.y * v;
        o2[(size_t)(4 * q + 2) * MM] = f.z * v;
        o2[(size_t)(4 * q + 3) * MM] = f.w * v;
    }
}

// kNN stage 1: per-node screening threshold from first-2048-point sample
__global__ __launch_bounds__(256) void k_knnT(const float4* __restrict__ pts4,
        const u32* __restrict__ idxA, float* __restrict__ Tarr) {
    int w = __builtin_amdgcn_readfirstlane(threadIdx.x >> 6);
    int g = blockIdx.x * 4 + w;                 // node 0..8191
    int b = g >> 11;
    int l = threadIdx.x & 63;
    const float4* pb = pts4 + (b << 14);
    float4 nd = pb[idxA[g]];
    float lm = 3.0e38f;
#pragma unroll 8
    for (int j = 0; j < 32; ++j) lm = fminf(lm, sfast(pb[l + 64 * j], nd));
    float T16 = kth16(lm, l);
    if (l == 0) Tarr[g] = T16 + 2.0f * EPS;
}

// kNN stage 2: sweep. node-per-lane, wave-uniform point stream (scalar loads).
// No LDS, no barriers. Survivors appended to per-node global list via atomics.
__global__ __launch_bounds__(256) void k_knnS(const float4* __restrict__ pts4,
        const u32* __restrict__ idxA, const float* __restrict__ Tarr,
        u32* __restrict__ qcnt, u32* __restrict__ q) {
    int bx = blockIdx.x;                        // 512 blocks
    int group = bx >> 2;                        // 64-node group, 0..127
    int w = __builtin_amdgcn_readfirstlane(threadIdx.x >> 6);
    int split = (bx & 3) * 4 + w;               // 0..15 (1024-pt range)
    int l = threadIdx.x & 63;
    int gn = group * 64 + l;                    // this lane's node
    int b = group >> 5;                         // batch (group within one batch)
    const float4* pb = pts4 + (b << 14);
    float4 nd = pb[idxA[gn]];
    float T = Tarr[gn];
    int base = __builtin_amdgcn_readfirstlane(split * 1024);
#pragma unroll 8
    for (int i = 0; i < 1024; ++i) {
        float4 p = pb[base + i];                // wave-uniform -> scalar load
        float d0 = p.x * nd.x;
        float d1 = fmaf(p.y, nd.y, d0);
        float d2 = fmaf(p.z, nd.z, d1);
        float s = fmaf(-2.0f, d2, p.w);
        if (s <= T) {
            u32 slot = atomicAdd(qcnt + gn, 1u);
            if (slot < QCAPG) q[(size_t)gn * QCAPG + slot] = (u32)(base + i);
        }
    }
}

// kNN stage 3: exact top-16 (numpy-exact keys, index tie-break) + feature max
__global__ __launch_bounds__(256) void k_knnM(const float4* __restrict__ pts4,
        const float* __restrict__ feat_t, const u32* __restrict__ idxA,
        const u32* __restrict__ qcnt, const u32* __restrict__ q, float* __restrict__ out) {
    int w = __builtin_amdgcn_readfirstlane(threadIdx.x >> 6);
    int g = blockIdx.x * 4 + w;                 // node 0..8191
    int b = g >> 11, m = g & (MM - 1);
    int l = threadIdx.x & 63;
    const float4* pb = pts4 + (b << 14);
    float4 nd = pb[idxA[g]];
    int cnt = (int)qcnt[g];
    if (cnt > QCAPG) cnt = QCAPG;
    const u32* qq = q + (size_t)g * QCAPG;
    u64 regk[QCAPG / 64];
#pragma unroll
    for (int s = 0; s < QCAPG / 64; ++s) {
        u64 kk = ~0ull;
        if ((s << 6) < cnt) {
            int pos = (s << 6) + l;
            if (pos < cnt) {
                u32 n = qq[pos];
                float d = np_dist(pb[n], nd);
                kk = ((u64)mono_bits(d) << 32) | (u64)n;
            }
        }
        regk[s] = kk;
    }
    float mx0 = -3.0e38f, mx1 = -3.0e38f;
    for (int it = 0; it < KNN; ++it) {
        u64 mykey = ~0ull;
#pragma unroll
        for (int s = 0; s < QCAPG / 64; ++s)
            if ((s << 6) < cnt) mykey = regk[s] < mykey ? regk[s] : mykey;
        u64 r = mykey;
#pragma unroll
        for (int j = 32; j > 0; j >>= 1) {
            u64 o = __shfl_xor(r, j);
            r = o < r ? o : r;
        }
#pragma unroll
        for (int s = 0; s < QCAPG / 64; ++s)
            if ((s << 6) < cnt) { if (regk[s] == r) regk[s] = ~0ull; }
        if (r != ~0ull) {
            u32 nj = (u32)(r & 0xFFFFFFFFull);
            const float2 f = *(const float2*)(feat_t + ((size_t)(b << 14) + nj) * CC + (l << 1));
            mx0 = fmaxf(mx0, f.x);
            mx1 = fmaxf(mx1, f.y);
        }
    }
    size_t ob = 49152 + ((size_t)(b * 256 + 128 + 2 * l)) * MM + m;
    out[ob] = mx0;
    out[ob + MM] = mx1;
}

extern "C" void kernel_launch(void* const* d_in, const int* in_sizes, int n_in,
                              void* d_out, int out_size, void* d_ws, size_t ws_size,
                              hipStream_t stream) {
    const float* coords = (const float*)d_in[0];
    const float* feats  = (const float*)d_in[1];
    const float* W      = (const float*)d_in[2];
    const float* bias   = (const float*)d_in[3];
    char* ws = (char*)d_ws;
    float*  feat_t = (float*)(ws + OFF_FEATT);
    float4* pts4   = (float4*)(ws + OFF_PTS4);
    float*  WT     = (float*)(ws + OFF_WT);
    u64*    keys   = (u64*)(ws + OFF_KEYS);
    u32*    vecU   = (u32*)(ws + OFF_VEC);
    u32*    idxA   = (u32*)(ws + OFF_IDX);
    float*  valA   = (float*)(ws + OFF_VAL);
    u64*    tmp1   = (u64*)(ws + OFF_TMP1);
    u64*    tmp2   = (u64*)(ws + OFF_TMP2);
    float*  Tarr   = (float*)(ws + OFF_T);
    u32*    qcnt   = (u32*)(ws + OFF_QCNT);
    u32*    q      = (u32*)(ws + OFF_Q);
    float*  out    = (float*)d_out;

    int prepN = BB * NN + CC * CC + BB * CC + BB * MM;
    k_prep     <<<(prepN + 255) / 256, 256, 0, stream>>>(coords, W, pts4, WT, vecU, qcnt);
    k_tv       <<<BB * (NN / 64), 256, 0, stream>>>(feats, WT, bias, feat_t, vecU);
    k_scores   <<<BB * NN / 256, 256, 0, stream>>>(feats, (const float*)vecU, keys);
    k_sortchunk<<<BB * 8, 512, 0, stream>>>(keys);
    k_mergetop <<<BB * 4, 512, 0, stream>>>(keys, tmp1, 2);
    k_mergetop <<<BB * 2, 512, 0, stream>>>(tmp1, tmp2, 1);
    k_mergefinal<<<BB, 512, 0, stream>>>(tmp2, idxA, valA);
    k_gather   <<<BB * MM / 256, 256, 0, stream>>>(pts4, feat_t, idxA, valA, out);
    k_knnT     <<<BB * MM / 4, 256, 0, stream>>>(pts4, idxA, Tarr);
    k_knnS     <<<512, 256, 0, stream>>>(pts4, idxA, Tarr, qcnt, q);
    k_knnM     <<<BB * MM / 4, 256, 0, stream>>>(pts4, feat_t, idxA, qcnt, q, out);
}

// Round 6
// 313.824 us; speedup vs baseline: 1.5755x; 1.5755x over previous
//
#include <hip/hip_runtime.h>
#include <hip/hip_bf16.h>
#include <stdint.h>

#define BB 4
#define NN 16384
#define CC 128
#define MM 2048
#define KNN 16
#define QCAP 512
#define EPS 1e-3f

typedef unsigned int u32;
typedef unsigned long long u64;

// ---- workspace layout (bytes) ----
#define OFF_FEATT   0ull                    // B*N*C f32   = 33554432
#define OFF_PTS4    33554432ull             // B*N float4  =  4194304
#define OFF_WT      37748736ull             // C*C f32     =    65536
#define OFF_KEYS    37814272ull             // B*N u64     =   524288
#define OFF_VEC     38338560ull             // B*C u32     =     2048
#define OFF_IDX     38340608ull             // B*M u32     =    32768
#define OFF_VAL     38373376ull             // B*M f32     =    32768
#define OFF_TMP1    38406144ull             // B*4*2048 u64=   262144
#define OFF_TMP2    38668288ull             // B*2*2048 u64=   131072

// numpy-exact f32 distance: ((pw + nw) - 2*(x*nx + y*ny + z*nz)), no FMA
__device__ __forceinline__ float np_dist(float4 p, float4 nd) {
#pragma clang fp contract(off)
    float dot = ((p.x * nd.x) + (p.y * nd.y)) + (p.z * nd.z);
    float d = (p.w + nd.w) - 2.0f * dot;
    return d;
}

// fast screening value s = -2*dot + p.w  (node-|n|^2 excluded; any rounding ok)
__device__ __forceinline__ float sfast(float4 p, float4 nd) {
    float dot = fmaf(p.x, nd.x, fmaf(p.y, nd.y, p.z * nd.z));
    return fmaf(-2.0f, dot, p.w);
}

__device__ __forceinline__ u32 mono_bits(float d) {
    u32 u = __float_as_uint(d);
    u ^= ((u32)(((int)u) >> 31)) | 0x80000000u;
    return u;
}

// 16th smallest of the 64 per-lane values (each lane-min covers disjoint points)
__device__ __forceinline__ float kth16(float v, int l) {
    float sv = v;
#pragma unroll
    for (int k = 2; k <= 64; k <<= 1) {
#pragma unroll
        for (int j = k >> 1; j > 0; j >>= 1) {
            float pv = __shfl_xor(sv, j);
            bool up = ((l & k) == 0);
            bool tmin = (((l & j) == 0) == up);
            float mn = fminf(sv, pv), mx = fmaxf(sv, pv);
            sv = tmin ? mn : mx;
        }
    }
    return __shfl(sv, 15);
}

// fused prep: pts4 (numpy-exact |p|^2), WT transpose, vecU zero
__global__ void k_prep(const float* __restrict__ coords, const float* __restrict__ W,
                       float4* __restrict__ pts4, float* __restrict__ WT,
                       u32* __restrict__ vecU) {
    int g = blockIdx.x * 256 + threadIdx.x;
    if (g < BB * NN) {
        int b = g >> 14, n = g & (NN - 1);
        const float* cb = coords + (size_t)b * 3 * NN;
        float x = cb[n], y = cb[NN + n], z = cb[2 * NN + n];
        float w;
        {
#pragma clang fp contract(off)
            w = ((x * x) + (y * y)) + (z * z);
        }
        pts4[g] = make_float4(x, y, z, w);
    } else if (g < BB * NN + CC * CC) {
        int i = g - BB * NN;
        int o = i >> 7, c = i & 127;
        WT[c * CC + o] = W[i];
    } else if (g < BB * NN + CC * CC + BB * CC) {
        vecU[g - BB * NN - CC * CC] = 0u;
    }
}

// fused transpose + vector-GEMV-max:
//   feat_t[b][n][c] = feats[b][c][n]; vector[b][o] = max_n relu(W@Z + b)
__global__ __launch_bounds__(256) void k_tv(const float* __restrict__ feats,
        const float* __restrict__ WT, const float* __restrict__ bias,
        float* __restrict__ feat_t, u32* __restrict__ vecU) {
    __shared__ float t[CC][65];
    int bx = blockIdx.x;                 // B * (N/64)
    int b = bx >> 8; int n0 = (bx & 255) * 64;
    int tid = threadIdx.x, l = tid & 63;
    int w = __builtin_amdgcn_readfirstlane(tid >> 6);
    const float* fb = feats + (size_t)b * CC * NN + n0;
    // load 128c x 64n tile (coalesced rows)
#pragma unroll
    for (int p = 0; p < 32; ++p) {
        int r = p * 4 + w;
        t[r][l] = fb[(size_t)r * NN + l];
    }
    __syncthreads();
    // write transposed (coalesced in c)
    float* ob = feat_t + ((size_t)b * NN + n0) * CC;
#pragma unroll
    for (int p = 0; p < 32; ++p) {
        int r = (p >> 1) * 4 + w;
        int c = (p & 1) * 64 + l;
        ob[(size_t)r * CC + c] = t[c][r];
    }
    // GEMV: wave w computes outputs [w*32, w*32+32) for all 64 n's
    int o0 = w * 32;
    float acc[32];
#pragma unroll
    for (int oi = 0; oi < 32; ++oi) acc[oi] = bias[o0 + oi];
    for (int c = 0; c < CC; ++c) {
        float zc = t[c][l];
        const float4* wt4 = (const float4*)(WT + c * CC + o0);
#pragma unroll
        for (int q = 0; q < 8; ++q) {
            float4 wv = wt4[q];
            acc[q * 4 + 0] = fmaf(wv.x, zc, acc[q * 4 + 0]);
            acc[q * 4 + 1] = fmaf(wv.y, zc, acc[q * 4 + 1]);
            acc[q * 4 + 2] = fmaf(wv.z, zc, acc[q * 4 + 2]);
            acc[q * 4 + 3] = fmaf(wv.w, zc, acc[q * 4 + 3]);
        }
    }
#pragma unroll
    for (int oi = 0; oi < 32; ++oi) {
        float rv = acc[oi] > 0.0f ? acc[oi] : 0.0f;   // relu, +0.0 guaranteed
#pragma unroll
        for (int s = 32; s; s >>= 1) rv = fmaxf(rv, __shfl_xor(rv, s));
        if (l == 0) atomicMax(vecU + b * CC + o0 + oi, __float_as_uint(rv));
    }
}

// keys[b][n] = (mono(sigmoid(sum_c feats*vector)) << 32) | (~n)
__global__ void k_scores(const float* __restrict__ feats, const float* __restrict__ vecF,
                         u64* __restrict__ keys) {
    int i = blockIdx.x * 256 + threadIdx.x;    // < B*N
    int b = i >> 14, n = i & (NN - 1);
    const float* fb = feats + (size_t)b * CC * NN + n;
    const float* vb = vecF + b * CC;
    float wsum = 0.f;
#pragma unroll 8
    for (int c = 0; c < CC; ++c) wsum = fmaf(fb[(size_t)c * NN], vb[c], wsum);
    float s = 1.0f / (1.0f + expf(-wsum));     // scores >= 0 -> bits monotonic
    u32 mono = __float_as_uint(s);
    keys[i] = ((u64)mono << 32) | (u64)(0xFFFFFFFFu - (u32)n);
}

// sort one 2048-key chunk descending, in place (32 blocks)
__global__ __launch_bounds__(512) void k_sortchunk(u64* __restrict__ keys) {
    __shared__ u64 sk[2048];
    int b = blockIdx.x >> 3, c = blockIdx.x & 7;
    int tid = threadIdx.x;
    u64* src = keys + (size_t)b * NN + c * 2048;
#pragma unroll
    for (int j = 0; j < 4; ++j) sk[tid + 512 * j] = src[tid + 512 * j];
    for (int size = 2; size <= 2048; size <<= 1) {
        for (int stride = size >> 1; stride > 0; stride >>= 1) {
            __syncthreads();
            for (int t = tid; t < 1024; t += 512) {
                int i = (t << 1) - (t & (stride - 1));
                int j = i + stride;
                u64 a = sk[i], cc = sk[j];
                bool up = ((i & size) == 0);
                if ((a < cc) == up) { sk[i] = cc; sk[j] = a; }
            }
        }
    }
    __syncthreads();
#pragma unroll
    for (int j = 0; j < 4; ++j) src[tid + 512 * j] = sk[tid + 512 * j];
}

// merge two descending 2048-lists -> top-2048 (descending)
__global__ __launch_bounds__(512) void k_mergetop(const u64* __restrict__ in,
        u64* __restrict__ outp, int lg /* log2(pairs per batch) */) {
    __shared__ u64 mk[4096];
    int b = blockIdx.x >> lg, pr = blockIdx.x & ((1 << lg) - 1);
    int tid = threadIdx.x;
    const u64* s0 = in + ((size_t)((b << lg) + pr) * 2) * 2048;
    const u64* s1 = s0 + 2048;
    for (int t = tid; t < 2048; t += 512) { mk[t] = s0[t]; mk[2048 + t] = s1[2047 - t]; }
    __syncthreads();
    for (int t = tid; t < 2048; t += 512) {
        u64 a = mk[t], c = mk[t + 2048];
        if (a < c) { mk[t] = c; mk[t + 2048] = a; }
    }
    for (int stride = 1024; stride > 0; stride >>= 1) {
        __syncthreads();
        for (int t = tid; t < 1024; t += 512) {
            int i = (t << 1) - (t & (stride - 1));
            int j = i + stride;
            u64 a = mk[i], c = mk[j];
            if (a < c) { mk[i] = c; mk[j] = a; }
        }
    }
    __syncthreads();
    u64* dst = outp + (size_t)((b << lg) + pr) * 2048;
    for (int t = tid; t < 2048; t += 512) dst[t] = mk[t];
}

// final merge -> idxA/valA
__global__ __launch_bounds__(512) void k_mergefinal(const u64* __restrict__ in,
        u32* __restrict__ idxA, float* __restrict__ valA) {
    __shared__ u64 mk[4096];
    int b = blockIdx.x, tid = threadIdx.x;
    const u64* s0 = in + (size_t)(b * 2) * 2048;
    const u64* s1 = s0 + 2048;
    for (int t = tid; t < 2048; t += 512) { mk[t] = s0[t]; mk[2048 + t] = s1[2047 - t]; }
    __syncthreads();
    for (int t = tid; t < 2048; t += 512) {
        u64 a = mk[t], c = mk[t + 2048];
        if (a < c) { mk[t] = c; mk[t + 2048] = a; }
    }
    for (int stride = 1024; stride > 0; stride >>= 1) {
        __syncthreads();
        for (int t = tid; t < 1024; t += 512) {
            int i = (t << 1) - (t & (stride - 1));
            int j = i + stride;
            u64 a = mk[i], c = mk[j];
            if (a < c) { mk[i] = c; mk[j] = a; }
        }
    }
    __syncthreads();
    for (int t = tid; t < 2048; t += 512) {
        u64 k = mk[t];
        idxA[b * MM + t] = 0xFFFFFFFFu - (u32)(k & 0xFFFFFFFFull);
        valA[b * MM + t] = __uint_as_float((u32)(k >> 32));
    }
}

// outputs 0,1 and first half of output 2
__global__ void k_gather(const float4* __restrict__ pts4, const float* __restrict__ feat_t,
        const u32* __restrict__ idxA, const float* __restrict__ valA, float* __restrict__ out) {
    int g = blockIdx.x * 256 + threadIdx.x;    // < B*M
    int b = g >> 11, i = g & (MM - 1);
    u32 n = idxA[g];
    float v = valA[g];
    float4 p = pts4[(b << 14) + (int)n];
    float* o0 = out + (size_t)b * 3 * MM + i;
    o0[0] = p.x; o0[MM] = p.y; o0[2 * MM] = p.z;
    float* o1 = o0 + 24576;
    o1[0] = p.x * v; o1[MM] = p.y * v; o1[2 * MM] = p.z * v;
    const float4* ft = (const float4*)(feat_t + ((size_t)(b << 14) + n) * CC);
    float* o2 = out + 49152 + ((size_t)b * 256) * MM + i;
#pragma unroll 8
    for (int q = 0; q < 32; ++q) {
        float4 f = ft[q];
        o2[(size_t)(4 * q + 0) * MM] = f.x * v;
        o2[(size_t)(4 * q + 1) * MM] = f.y * v;
        o2[(size_t)(4 * q + 2) * MM] = f.z * v;
        o2[(size_t)(4 * q + 3) * MM] = f.w * v;
    }
}

#define PROC(nid, ndv, Tv, qcv) { \
    float dt = fmaf(p.x, ndv.x, fmaf(p.y, ndv.y, p.z * ndv.z)); \
    float sv_ = fmaf(-2.0f, dt, p.w); \
    bool pred = (sv_ <= Tv); \
    u64 bal = __ballot(pred); \
    if (bal) { \
        if (pred) { \
            int off = (int)__popcll(bal & ((1ull << l) - 1ull)); \
            int slot = qcv + off; \
            if (slot < QCAP) qS[w * 4 + nid][slot] = (u32)n; \
        } \
        qcv += (int)__popcll(bal); \
    } }

// kNN(k=16) + channel-max aggregation -> second half of output 2
// 16 nodes/block (4/wave); fast FMA screening; exact recompute on survivors.
// LDS = 16KB pts + 32KB queues -> 3 blocks/CU.
__global__ __launch_bounds__(256) void k_knn(const float4* __restrict__ pts4,
        const float* __restrict__ feat_t, const u32* __restrict__ idxA, float* __restrict__ out) {
    __shared__ float4 ptsS[1024];
    __shared__ u32 qS[16][QCAP];
    __shared__ float4 nodeS[16];
    int bx = blockIdx.x;
    int b = bx >> 7, mblk = bx & 127;
    int tid = threadIdx.x, l = tid & 63;
    const float4* pb = pts4 + (b << 14);
    if (tid < 16) nodeS[tid] = pb[idxA[b * MM + mblk * 16 + tid]];
#pragma unroll
    for (int j = 0; j < 4; ++j) ptsS[tid + 256 * j] = pb[tid + 256 * j];
    __syncthreads();
    int w = __builtin_amdgcn_readfirstlane(tid >> 6);
    float4 nd0 = nodeS[w * 4 + 0];
    float4 nd1 = nodeS[w * 4 + 1];
    float4 nd2 = nodeS[w * 4 + 2];
    float4 nd3 = nodeS[w * 4 + 3];
    // pass 1: per-lane mins over sample (first 2048 pts), per node
    float lm0 = 3e38f, lm1 = 3e38f, lm2 = 3e38f, lm3 = 3e38f;
#pragma unroll 4
    for (int j = 0; j < 16; ++j) {
        float4 p = ptsS[l + 64 * j];
        lm0 = fminf(lm0, sfast(p, nd0));
        lm1 = fminf(lm1, sfast(p, nd1));
        lm2 = fminf(lm2, sfast(p, nd2));
        lm3 = fminf(lm3, sfast(p, nd3));
    }
    __syncthreads();
#pragma unroll
    for (int j = 0; j < 4; ++j) ptsS[tid + 256 * j] = pb[1024 + tid + 256 * j];
    __syncthreads();
#pragma unroll 4
    for (int j = 0; j < 16; ++j) {
        float4 p = ptsS[l + 64 * j];
        lm0 = fminf(lm0, sfast(p, nd0));
        lm1 = fminf(lm1, sfast(p, nd1));
        lm2 = fminf(lm2, sfast(p, nd2));
        lm3 = fminf(lm3, sfast(p, nd3));
    }
    float T0 = kth16(lm0, l) + 2.0f * EPS;
    float T1 = kth16(lm1, l) + 2.0f * EPS;
    float T2 = kth16(lm2, l) + 2.0f * EPS;
    float T3 = kth16(lm3, l) + 2.0f * EPS;
    // pass 2: sweep all 16 chunks, compact survivor indices per node
    int qc0 = 0, qc1 = 0, qc2 = 0, qc3 = 0;
    for (int ch = 0; ch < 16; ++ch) {
        __syncthreads();
#pragma unroll
        for (int j = 0; j < 4; ++j) ptsS[tid + 256 * j] = pb[ch * 1024 + tid + 256 * j];
        __syncthreads();
        for (int j = 0; j < 16; ++j) {
            float4 p = ptsS[l + 64 * j];
            int n = ch * 1024 + l + 64 * j;
            PROC(0, nd0, T0, qc0)
            PROC(1, nd1, T1, qc1)
            PROC(2, nd2, T2, qc2)
            PROC(3, nd3, T3, qc3)
        }
    }
    // pass 3: per node, exact keys for survivors, 16x wave-argmin + feature max
    float4 ndA[4] = {nd0, nd1, nd2, nd3};
    int qcA[4] = {qc0 < QCAP ? qc0 : QCAP, qc1 < QCAP ? qc1 : QCAP,
                  qc2 < QCAP ? qc2 : QCAP, qc3 < QCAP ? qc3 : QCAP};
#pragma unroll
    for (int nid = 0; nid < 4; ++nid) {
        float4 nd = ndA[nid];
        int qcap = qcA[nid];
        const u32* qq = qS[w * 4 + nid];
        u64 regk[QCAP / 64];
#pragma unroll
        for (int s = 0; s < QCAP / 64; ++s) {
            u64 kk = ~0ull;
            if ((s << 6) < qcap) {
                int pos = (s << 6) + l;
                if (pos < qcap) {
                    u32 n = qq[pos];
                    float d = np_dist(pb[n], nd);
                    kk = ((u64)mono_bits(d) << 32) | (u64)n;
                }
            }
            regk[s] = kk;
        }
        float mx0 = -3.0e38f, mx1 = -3.0e38f;
        for (int it = 0; it < KNN; ++it) {
            u64 mykey = ~0ull;
#pragma unroll
            for (int s = 0; s < QCAP / 64; ++s)
                if ((s << 6) < qcap) mykey = regk[s] < mykey ? regk[s] : mykey;
            u64 r = mykey;
#pragma unroll
            for (int j = 32; j > 0; j >>= 1) {
                u64 o = __shfl_xor(r, j);
                r = o < r ? o : r;
            }
#pragma unroll
            for (int s = 0; s < QCAP / 64; ++s)
                if ((s << 6) < qcap) { if (regk[s] == r) regk[s] = ~0ull; }
            if (r != ~0ull) {
                u32 nj = (u32)(r & 0xFFFFFFFFull);
                const float2 f = *(const float2*)(feat_t + ((size_t)(b << 14) + nj) * CC + (l << 1));
                mx0 = fmaxf(mx0, f.x);
                mx1 = fmaxf(mx1, f.y);
            }
        }
        int m = mblk * 16 + w * 4 + nid;
        size_t ob = 49152 + ((size_t)(b * 256 + 128 + 2 * l)) * MM + m;
        out[ob] = mx0;
        out[ob + MM] = mx1;
    }
}

extern "C" void kernel_launch(void* const* d_in, const int* in_sizes, int n_in,
                              void* d_out, int out_size, void* d_ws, size_t ws_size,
                              hipStream_t stream) {
    const float* coords = (const float*)d_in[0];
    const float* feats  = (const float*)d_in[1];
    const float* W      = (const float*)d_in[2];
    const float* bias   = (const float*)d_in[3];
    char* ws = (char*)d_ws;
    float*  feat_t = (float*)(ws + OFF_FEATT);
    float4* pts4   = (float4*)(ws + OFF_PTS4);
    float*  WT     = (float*)(ws + OFF_WT);
    u64*    keys   = (u64*)(ws + OFF_KEYS);
    u32*    vecU   = (u32*)(ws + OFF_VEC);
    u32*    idxA   = (u32*)(ws + OFF_IDX);
    float*  valA   = (float*)(ws + OFF_VAL);
    u64*    tmp1   = (u64*)(ws + OFF_TMP1);
    u64*    tmp2   = (u64*)(ws + OFF_TMP2);
    float*  out    = (float*)d_out;

    int prepN = BB * NN + CC * CC + BB * CC;
    k_prep     <<<(prepN + 255) / 256, 256, 0, stream>>>(coords, W, pts4, WT, vecU);
    k_tv       <<<BB * (NN / 64), 256, 0, stream>>>(feats, WT, bias, feat_t, vecU);
    k_scores   <<<BB * NN / 256, 256, 0, stream>>>(feats, (const float*)vecU, keys);
    k_sortchunk<<<BB * 8, 512, 0, stream>>>(keys);
    k_mergetop <<<BB * 4, 512, 0, stream>>>(keys, tmp1, 2);
    k_mergetop <<<BB * 2, 512, 0, stream>>>(tmp1, tmp2, 1);
    k_mergefinal<<<BB, 512, 0, stream>>>(tmp2, idxA, valA);
    k_gather   <<<BB * MM / 256, 256, 0, stream>>>(pts4, feat_t, idxA, valA, out);
    k_knn      <<<BB * (MM / 16), 256, 0, stream>>>(pts4, feat_t, idxA, out);
}

// Round 7
// 274.651 us; speedup vs baseline: 1.8002x; 1.1426x over previous
//
#include <hip/hip_runtime.h>
#include <hip/hip_bf16.h>
#include <stdint.h>

#define BB 4
#define NN 16384
#define CC 128
#define MM 2048
#define KNN 16
#define QCAP 512
#define EPS 1e-3f

typedef unsigned int u32;
typedef unsigned short u16;
typedef unsigned long long u64;

// ---- workspace layout (bytes) ----
#define OFF_FEATT   0ull                    // B*N*C f32   = 33554432
#define OFF_PTS4    33554432ull             // B*N float4  =  4194304
#define OFF_WT      37748736ull             // C*C f32     =    65536
#define OFF_KEYS    37814272ull             // B*N u64     =   524288
#define OFF_VEC     38338560ull             // B*C u32     =     2048
#define OFF_IDX     38340608ull             // B*M u32     =    32768
#define OFF_VAL     38373376ull             // B*M f32     =    32768
#define OFF_TMP1    38406144ull             // B*4*2048 u64=   262144
#define OFF_TMP2    38668288ull             // B*2*2048 u64=   131072

// numpy-exact f32 distance: ((pw + nw) - 2*(x*nx + y*ny + z*nz)), no FMA
__device__ __forceinline__ float np_dist(float4 p, float4 nd) {
#pragma clang fp contract(off)
    float dot = ((p.x * nd.x) + (p.y * nd.y)) + (p.z * nd.z);
    float d = (p.w + nd.w) - 2.0f * dot;
    return d;
}

// fast screening value s = -2*dot + p.w  (node-|n|^2 excluded; any rounding ok)
__device__ __forceinline__ float sfast(float4 p, float4 nd) {
    float dot = fmaf(p.x, nd.x, fmaf(p.y, nd.y, p.z * nd.z));
    return fmaf(-2.0f, dot, p.w);
}

__device__ __forceinline__ u32 mono_bits(float d) {
    u32 u = __float_as_uint(d);
    u ^= ((u32)(((int)u) >> 31)) | 0x80000000u;
    return u;
}

// 16th smallest of the 64 per-lane values (each lane-min covers disjoint points)
__device__ __forceinline__ float kth16(float v, int l) {
    float sv = v;
#pragma unroll
    for (int k = 2; k <= 64; k <<= 1) {
#pragma unroll
        for (int j = k >> 1; j > 0; j >>= 1) {
            float pv = __shfl_xor(sv, j);
            bool up = ((l & k) == 0);
            bool tmin = (((l & j) == 0) == up);
            float mn = fminf(sv, pv), mx = fmaxf(sv, pv);
            sv = tmin ? mn : mx;
        }
    }
    return __shfl(sv, 15);
}

// fused prep: pts4 (numpy-exact |p|^2), WT transpose, vecU zero
__global__ void k_prep(const float* __restrict__ coords, const float* __restrict__ W,
                       float4* __restrict__ pts4, float* __restrict__ WT,
                       u32* __restrict__ vecU) {
    int g = blockIdx.x * 256 + threadIdx.x;
    if (g < BB * NN) {
        int b = g >> 14, n = g & (NN - 1);
        const float* cb = coords + (size_t)b * 3 * NN;
        float x = cb[n], y = cb[NN + n], z = cb[2 * NN + n];
        float w;
        {
#pragma clang fp contract(off)
            w = ((x * x) + (y * y)) + (z * z);
        }
        pts4[g] = make_float4(x, y, z, w);
    } else if (g < BB * NN + CC * CC) {
        int i = g - BB * NN;
        int o = i >> 7, c = i & 127;
        WT[c * CC + o] = W[i];
    } else if (g < BB * NN + CC * CC + BB * CC) {
        vecU[g - BB * NN - CC * CC] = 0u;
    }
}

// fused transpose + vector-GEMV-max:
//   feat_t[b][n][c] = feats[b][c][n]; vector[b][o] = max_n relu(W@Z + b)
__global__ __launch_bounds__(256) void k_tv(const float* __restrict__ feats,
        const float* __restrict__ WT, const float* __restrict__ bias,
        float* __restrict__ feat_t, u32* __restrict__ vecU) {
    __shared__ float t[CC][65];
    int bx = blockIdx.x;                 // B * (N/64)
    int b = bx >> 8; int n0 = (bx & 255) * 64;
    int tid = threadIdx.x, l = tid & 63;
    int w = __builtin_amdgcn_readfirstlane(tid >> 6);
    const float* fb = feats + (size_t)b * CC * NN + n0;
    // load 128c x 64n tile (coalesced rows)
#pragma unroll
    for (int p = 0; p < 32; ++p) {
        int r = p * 4 + w;
        t[r][l] = fb[(size_t)r * NN + l];
    }
    __syncthreads();
    // write transposed (coalesced in c)
    float* ob = feat_t + ((size_t)b * NN + n0) * CC;
#pragma unroll
    for (int p = 0; p < 32; ++p) {
        int r = (p >> 1) * 4 + w;
        int c = (p & 1) * 64 + l;
        ob[(size_t)r * CC + c] = t[c][r];
    }
    // GEMV: wave w computes outputs [w*32, w*32+32) for all 64 n's
    int o0 = w * 32;
    float acc[32];
#pragma unroll
    for (int oi = 0; oi < 32; ++oi) acc[oi] = bias[o0 + oi];
    for (int c = 0; c < CC; ++c) {
        float zc = t[c][l];
        const float4* wt4 = (const float4*)(WT + c * CC + o0);
#pragma unroll
        for (int q = 0; q < 8; ++q) {
            float4 wv = wt4[q];
            acc[q * 4 + 0] = fmaf(wv.x, zc, acc[q * 4 + 0]);
            acc[q * 4 + 1] = fmaf(wv.y, zc, acc[q * 4 + 1]);
            acc[q * 4 + 2] = fmaf(wv.z, zc, acc[q * 4 + 2]);
            acc[q * 4 + 3] = fmaf(wv.w, zc, acc[q * 4 + 3]);
        }
    }
#pragma unroll
    for (int oi = 0; oi < 32; ++oi) {
        float rv = acc[oi] > 0.0f ? acc[oi] : 0.0f;   // relu, +0.0 guaranteed
#pragma unroll
        for (int s = 32; s; s >>= 1) rv = fmaxf(rv, __shfl_xor(rv, s));
        if (l == 0) atomicMax(vecU + b * CC + o0 + oi, __float_as_uint(rv));
    }
}

// keys[b][n] = (mono(sigmoid(sum_c feats*vector)) << 32) | (~n)
__global__ void k_scores(const float* __restrict__ feats, const float* __restrict__ vecF,
                         u64* __restrict__ keys) {
    int i = blockIdx.x * 256 + threadIdx.x;    // < B*N
    int b = i >> 14, n = i & (NN - 1);
    const float* fb = feats + (size_t)b * CC * NN + n;
    const float* vb = vecF + b * CC;
    float wsum = 0.f;
#pragma unroll 8
    for (int c = 0; c < CC; ++c) wsum = fmaf(fb[(size_t)c * NN], vb[c], wsum);
    float s = 1.0f / (1.0f + expf(-wsum));     // scores >= 0 -> bits monotonic
    u32 mono = __float_as_uint(s);
    keys[i] = ((u64)mono << 32) | (u64)(0xFFFFFFFFu - (u32)n);
}

// sort one 2048-key chunk descending, in place (32 blocks, 1024 thr)
__global__ __launch_bounds__(1024) void k_sortchunk(u64* __restrict__ keys) {
    __shared__ u64 sk[2048];
    int b = blockIdx.x >> 3, c = blockIdx.x & 7;
    int tid = threadIdx.x;
    u64* src = keys + (size_t)b * NN + c * 2048;
    sk[tid] = src[tid];
    sk[tid + 1024] = src[tid + 1024];
    for (int size = 2; size <= 2048; size <<= 1) {
        for (int stride = size >> 1; stride > 0; stride >>= 1) {
            __syncthreads();
            int t = tid;
            int i = (t << 1) - (t & (stride - 1));
            int j = i + stride;
            u64 a = sk[i], cc = sk[j];
            bool up = ((i & size) == 0);
            if ((a < cc) == up) { sk[i] = cc; sk[j] = a; }
        }
    }
    __syncthreads();
    src[tid] = sk[tid];
    src[tid + 1024] = sk[tid + 1024];
}

// merge two descending 2048-lists -> top-2048 (descending)
__global__ __launch_bounds__(512) void k_mergetop(const u64* __restrict__ in,
        u64* __restrict__ outp, int lg /* log2(pairs per batch) */) {
    __shared__ u64 mk[4096];
    int b = blockIdx.x >> lg, pr = blockIdx.x & ((1 << lg) - 1);
    int tid = threadIdx.x;
    const u64* s0 = in + ((size_t)((b << lg) + pr) * 2) * 2048;
    const u64* s1 = s0 + 2048;
    for (int t = tid; t < 2048; t += 512) { mk[t] = s0[t]; mk[2048 + t] = s1[2047 - t]; }
    __syncthreads();
    for (int t = tid; t < 2048; t += 512) {
        u64 a = mk[t], c = mk[t + 2048];
        if (a < c) { mk[t] = c; mk[t + 2048] = a; }
    }
    for (int stride = 1024; stride > 0; stride >>= 1) {
        __syncthreads();
        for (int t = tid; t < 1024; t += 512) {
            int i = (t << 1) - (t & (stride - 1));
            int j = i + stride;
            u64 a = mk[i], c = mk[j];
            if (a < c) { mk[i] = c; mk[j] = a; }
        }
    }
    __syncthreads();
    u64* dst = outp + (size_t)((b << lg) + pr) * 2048;
    for (int t = tid; t < 2048; t += 512) dst[t] = mk[t];
}

// final merge -> idxA/valA
__global__ __launch_bounds__(512) void k_mergefinal(const u64* __restrict__ in,
        u32* __restrict__ idxA, float* __restrict__ valA) {
    __shared__ u64 mk[4096];
    int b = blockIdx.x, tid = threadIdx.x;
    const u64* s0 = in + (size_t)(b * 2) * 2048;
    const u64* s1 = s0 + 2048;
    for (int t = tid; t < 2048; t += 512) { mk[t] = s0[t]; mk[2048 + t] = s1[2047 - t]; }
    __syncthreads();
    for (int t = tid; t < 2048; t += 512) {
        u64 a = mk[t], c = mk[t + 2048];
        if (a < c) { mk[t] = c; mk[t + 2048] = a; }
    }
    for (int stride = 1024; stride > 0; stride >>= 1) {
        __syncthreads();
        for (int t = tid; t < 1024; t += 512) {
            int i = (t << 1) - (t & (stride - 1));
            int j = i + stride;
            u64 a = mk[i], c = mk[j];
            if (a < c) { mk[i] = c; mk[j] = a; }
        }
    }
    __syncthreads();
    for (int t = tid; t < 2048; t += 512) {
        u64 k = mk[t];
        idxA[b * MM + t] = 0xFFFFFFFFu - (u32)(k & 0xFFFFFFFFull);
        valA[b * MM + t] = __uint_as_float((u32)(k >> 32));
    }
}

// outputs 0,1 and first half of output 2
__global__ void k_gather(const float4* __restrict__ pts4, const float* __restrict__ feat_t,
        const u32* __restrict__ idxA, const float* __restrict__ valA, float* __restrict__ out) {
    int g = blockIdx.x * 256 + threadIdx.x;    // < B*M
    int b = g >> 11, i = g & (MM - 1);
    u32 n = idxA[g];
    float v = valA[g];
    float4 p = pts4[(b << 14) + (int)n];
    float* o0 = out + (size_t)b * 3 * MM + i;
    o0[0] = p.x; o0[MM] = p.y; o0[2 * MM] = p.z;
    float* o1 = o0 + 24576;
    o1[0] = p.x * v; o1[MM] = p.y * v; o1[2 * MM] = p.z * v;
    const float4* ft = (const float4*)(feat_t + ((size_t)(b << 14) + n) * CC);
    float* o2 = out + 49152 + ((size_t)b * 256) * MM + i;
#pragma unroll 8
    for (int q = 0; q < 32; ++q) {
        float4 f = ft[q];
        o2[(size_t)(4 * q + 0) * MM] = f.x * v;
        o2[(size_t)(4 * q + 1) * MM] = f.y * v;
        o2[(size_t)(4 * q + 2) * MM] = f.z * v;
        o2[(size_t)(4 * q + 3) * MM] = f.w * v;
    }
}

// kNN(k=16) + channel-max aggregation -> second half of output 2
// 4 nodes/block (1/wave); u16 LDS queues; 20.5KB LDS -> 7 blocks/CU; grid 2048.
__global__ __launch_bounds__(256, 7) void k_knn(const float4* __restrict__ pts4,
        const float* __restrict__ feat_t, const u32* __restrict__ idxA, float* __restrict__ out) {
    __shared__ float4 ptsS[1024];
    __shared__ u16 qS[4][QCAP];
    __shared__ float4 nodeS[4];
    int bx = blockIdx.x;
    int b = bx >> 9, mblk = bx & 511;
    int tid = threadIdx.x, l = tid & 63;
    const float4* pb = pts4 + (b << 14);
    if (tid < 4) nodeS[tid] = pb[idxA[b * MM + mblk * 4 + tid]];
#pragma unroll
    for (int j = 0; j < 4; ++j) ptsS[tid + 256 * j] = pb[tid + 256 * j];
    __syncthreads();
    int w = __builtin_amdgcn_readfirstlane(tid >> 6);
    float4 nd = nodeS[w];
    // pass 1: per-lane min over 2048-pt sample -> 16th-smallest -> threshold
    float lm = 3.0e38f;
#pragma unroll 4
    for (int j = 0; j < 16; ++j) lm = fminf(lm, sfast(ptsS[l + 64 * j], nd));
    __syncthreads();
#pragma unroll
    for (int j = 0; j < 4; ++j) ptsS[tid + 256 * j] = pb[1024 + tid + 256 * j];
    __syncthreads();
#pragma unroll 4
    for (int j = 0; j < 16; ++j) lm = fminf(lm, sfast(ptsS[l + 64 * j], nd));
    float T = kth16(lm, l) + 2.0f * EPS;
    // pass 2: sweep all 16 chunks, compact survivor u16 indices per node
    int qc = 0;
    for (int ch = 0; ch < 16; ++ch) {
        __syncthreads();
#pragma unroll
        for (int j = 0; j < 4; ++j) ptsS[tid + 256 * j] = pb[ch * 1024 + tid + 256 * j];
        __syncthreads();
        for (int j = 0; j < 16; ++j) {
            float4 p = ptsS[l + 64 * j];
            float dt = fmaf(p.x, nd.x, fmaf(p.y, nd.y, p.z * nd.z));
            float s = fmaf(-2.0f, dt, p.w);
            bool pred = (s <= T);
            u64 bal = __ballot(pred);
            if (bal) {
                if (pred) {
                    int off = __builtin_amdgcn_mbcnt_hi((u32)(bal >> 32),
                              __builtin_amdgcn_mbcnt_lo((u32)bal, 0));
                    int slot = qc + off;
                    if (slot < QCAP) qS[w][slot] = (u16)(ch * 1024 + l + 64 * j);
                }
                qc += (int)__popcll(bal);
            }
        }
    }
    // pass 3: exact keys (numpy-exact d, index tie-break), 16x wave-argmin + feat max
    int cnt = qc < QCAP ? qc : QCAP;
    u64 regk[QCAP / 64];
#pragma unroll
    for (int s = 0; s < QCAP / 64; ++s) {
        u64 kk = ~0ull;
        if ((s << 6) < cnt) {
            int pos = (s << 6) + l;
            if (pos < cnt) {
                u32 n = qS[w][pos];
                float d = np_dist(pb[n], nd);
                kk = ((u64)mono_bits(d) << 32) | (u64)n;
            }
        }
        regk[s] = kk;
    }
    float mx0 = -3.0e38f, mx1 = -3.0e38f;
    for (int it = 0; it < KNN; ++it) {
        u64 mykey = ~0ull;
#pragma unroll
        for (int s = 0; s < QCAP / 64; ++s)
            if ((s << 6) < cnt) mykey = regk[s] < mykey ? regk[s] : mykey;
        u64 r = mykey;
#pragma unroll
        for (int j = 32; j > 0; j >>= 1) {
            u64 o = __shfl_xor(r, j);
            r = o < r ? o : r;
        }
#pragma unroll
        for (int s = 0; s < QCAP / 64; ++s)
            if ((s << 6) < cnt) { if (regk[s] == r) regk[s] = ~0ull; }
        if (r != ~0ull) {
            u32 nj = (u32)(r & 0xFFFFFFFFull);
            const float2 f = *(const float2*)(feat_t + ((size_t)(b << 14) + nj) * CC + (l << 1));
            mx0 = fmaxf(mx0, f.x);
            mx1 = fmaxf(mx1, f.y);
        }
    }
    int m = mblk * 4 + w;
    size_t ob = 49152 + ((size_t)(b * 256 + 128 + 2 * l)) * MM + m;
    out[ob] = mx0;
    out[ob + MM] = mx1;
}

extern "C" void kernel_launch(void* const* d_in, const int* in_sizes, int n_in,
                              void* d_out, int out_size, void* d_ws, size_t ws_size,
                              hipStream_t stream) {
    const float* coords = (const float*)d_in[0];
    const float* feats  = (const float*)d_in[1];
    const float* W      = (const float*)d_in[2];
    const float* bias   = (const float*)d_in[3];
    char* ws = (char*)d_ws;
    float*  feat_t = (float*)(ws + OFF_FEATT);
    float4* pts4   = (float4*)(ws + OFF_PTS4);
    float*  WT     = (float*)(ws + OFF_WT);
    u64*    keys   = (u64*)(ws + OFF_KEYS);
    u32*    vecU   = (u32*)(ws + OFF_VEC);
    u32*    idxA   = (u32*)(ws + OFF_IDX);
    float*  valA   = (float*)(ws + OFF_VAL);
    u64*    tmp1   = (u64*)(ws + OFF_TMP1);
    u64*    tmp2   = (u64*)(ws + OFF_TMP2);
    float*  out    = (float*)d_out;

    int prepN = BB * NN + CC * CC + BB * CC;
    k_prep     <<<(prepN + 255) / 256, 256, 0, stream>>>(coords, W, pts4, WT, vecU);
    k_tv       <<<BB * (NN / 64), 256, 0, stream>>>(feats, WT, bias, feat_t, vecU);
    k_scores   <<<BB * NN / 256, 256, 0, stream>>>(feats, (const float*)vecU, keys);
    k_sortchunk<<<BB * 8, 1024, 0, stream>>>(keys);
    k_mergetop <<<BB * 4, 512, 0, stream>>>(keys, tmp1, 2);
    k_mergetop <<<BB * 2, 512, 0, stream>>>(tmp1, tmp2, 1);
    k_mergefinal<<<BB, 512, 0, stream>>>(tmp2, idxA, valA);
    k_gather   <<<BB * MM / 256, 256, 0, stream>>>(pts4, feat_t, idxA, valA, out);
    k_knn      <<<BB * (MM / 4), 256, 0, stream>>>(pts4, feat_t, idxA, out);
}